// Round 2
// baseline (296.527 us; speedup 1.0000x reference)
//
#include <hip/hip_runtime.h>

typedef __bf16 bf16x8 __attribute__((ext_vector_type(8)));
typedef float f32x4 __attribute__((ext_vector_type(4)));
typedef unsigned short u16;
typedef unsigned int u32;

__device__ __forceinline__ u16 f2bf(float f) {
  u32 u = __builtin_bit_cast(u32, f);
  u = (u + 0x7FFFu + ((u >> 16) & 1u)) >> 16;
  return (u16)u;
}

__device__ __forceinline__ void gload_lds16(const void* g, void* l) {
  __builtin_amdgcn_global_load_lds((const __attribute__((address_space(1))) void*)g,
                                   (__attribute__((address_space(3))) void*)l, 16, 0, 0);
}

// ---------------------------------------------------------------------------
// Transpose + cast: src fp32 [b][1024 i][1024 n] -> dst bf16 [b][1024 n][1024 i]
// grid (16 n-tiles, 16 i-tiles, 8 b), block 256
// ---------------------------------------------------------------------------
__global__ __launch_bounds__(256) void transpose_cast(const float* __restrict__ src,
                                                      u16* __restrict__ dst) {
  __shared__ float T[64][68];
  int tid = threadIdx.x;
  int n0 = blockIdx.x * 64, i0 = blockIdx.y * 64;
  size_t boff = (size_t)blockIdx.z << 20;
  const float* s = src + boff;
  u16* d = dst + boff;
  int ir = tid >> 4, n4 = (tid & 15) * 4;
#pragma unroll
  for (int r = 0; r < 4; ++r) {
    int i_loc = ir + r * 16;
    float4 v = *(const float4*)(s + (size_t)(i0 + i_loc) * 1024 + n0 + n4);
    *(float4*)&T[i_loc][n4] = v;
  }
  __syncthreads();
  int nr = tid >> 3, i8 = (tid & 7) * 8;
#pragma unroll
  for (int r = 0; r < 2; ++r) {
    int n_loc = nr + r * 32;
    u32 pk[4];
#pragma unroll
    for (int j = 0; j < 4; ++j) {
      float f0 = T[i8 + 2 * j][n_loc];
      float f1 = T[i8 + 2 * j + 1][n_loc];
      pk[j] = (u32)f2bf(f0) | ((u32)f2bf(f1) << 16);
    }
    *(uint4*)(d + (size_t)(n0 + n_loc) * 1024 + i0 + i8) = make_uint4(pk[0], pk[1], pk[2], pk[3]);
  }
}

// ---------------------------------------------------------------------------
// Cast weights to bf16. w=0..2: Wq/Wk/Wv as-is [o][i]. w=3: Wm' permuted so
// column c' = h*64+d maps to Wm column d*16+h (head-major K for final GEMM).
// grid (1024 rows, 4 weights), block 256 (4 cols/thread)
// ---------------------------------------------------------------------------
__global__ __launch_bounds__(256) void cast_weights(const float* __restrict__ Wq,
                                                    const float* __restrict__ Wk,
                                                    const float* __restrict__ Wv,
                                                    const float* __restrict__ Wm,
                                                    u16* __restrict__ out) {
  int w = blockIdx.y;
  const float* src = (w == 0) ? Wq : (w == 1) ? Wk : (w == 2) ? Wv : Wm;
  u16* dst = out + ((size_t)w << 20);
  int o = blockIdx.x;
  int c4 = threadIdx.x * 4;
  float f[4];
  if (w < 3) {
    float4 v = *(const float4*)(src + (size_t)o * 1024 + c4);
    f[0] = v.x; f[1] = v.y; f[2] = v.z; f[3] = v.w;
  } else {
#pragma unroll
    for (int j = 0; j < 4; ++j) {
      int cp = c4 + j;
      f[j] = src[(size_t)o * 1024 + (cp & 63) * 16 + (cp >> 6)];
    }
  }
  u32 p0 = (u32)f2bf(f[0]) | ((u32)f2bf(f[1]) << 16);
  u32 p1 = (u32)f2bf(f[2]) | ((u32)f2bf(f[3]) << 16);
  *(uint2*)(dst + (size_t)o * 1024 + c4) = make_uint2(p0, p1);
}

// ---------------------------------------------------------------------------
// bt-GEMM: C[c,n] = sum_k A[c,k] * B^T[n,k] (+bias), 128x128 tile, BK=32,
// 4 waves (2x2 of 64x64), mfma 16x16x32 bf16, global_load_lds staging.
// BMODE 0: B^T = plain [b][n][k] (Xt).  BMODE 1: B^T[n][c'] from attention
//          output Xh[b][h][n][d] with c' = h*64+d.
// OMODE 0: bf16 -> [b][h][n][d] (Q,K)   OMODE 1: bf16 -> [b][h][d][n] (V)
// OMODE 2: fp32 -> [b][c][n] (final out)
// grid (8 n-tiles, 8 c-tiles, 8 b), block 256
// ---------------------------------------------------------------------------
template <int BMODE, int OMODE>
__global__ __launch_bounds__(256) void gemm_bt(const u16* __restrict__ A,
                                               const u16* __restrict__ Bsrc,
                                               const float* __restrict__ bias,
                                               void* __restrict__ Out, float escale) {
  __shared__ u16 As[128 * 32];
  __shared__ u16 Bs[128 * 32];
  int tid = threadIdx.x;
  int wave = tid >> 6;
  int l = tid & 63, ln = l & 15, g = l >> 4;
  int n0 = blockIdx.x * 128, c0 = blockIdx.y * 128;
  size_t b = blockIdx.z;
  const u16* Bb = Bsrc + (b << 20);
  int wr = (wave >> 1) * 64, wc = (wave & 1) * 64;
  f32x4 acc[4][4] = {};
  for (int kt = 0; kt < 32; ++kt) {
#pragma unroll
    for (int i = 0; i < 2; ++i) {
      int e = i * 256 + tid;
      int row = e >> 2;
      int ko = (e & 3) * 8;
      gload_lds16(A + (size_t)(c0 + row) * 1024 + kt * 32 + ko,
                  &As[(i * 256 + wave * 64) * 8]);
      const u16* gb;
      if (BMODE == 0)
        gb = Bb + (size_t)(n0 + row) * 1024 + kt * 32 + ko;
      else
        gb = Bb + ((size_t)(kt >> 1) << 16) + (size_t)(n0 + row) * 64 + (kt & 1) * 32 + ko;
      gload_lds16(gb, &Bs[(i * 256 + wave * 64) * 8]);
    }
    __syncthreads();
    bf16x8 af[4], bfr[4];
#pragma unroll
    for (int m = 0; m < 4; ++m) af[m] = *(const bf16x8*)&As[(wr + m * 16 + ln) * 32 + g * 8];
#pragma unroll
    for (int n = 0; n < 4; ++n) bfr[n] = *(const bf16x8*)&Bs[(wc + n * 16 + ln) * 32 + g * 8];
#pragma unroll
    for (int m = 0; m < 4; ++m)
#pragma unroll
      for (int n = 0; n < 4; ++n)
        acc[m][n] = __builtin_amdgcn_mfma_f32_16x16x32_bf16(af[m], bfr[n], acc[m][n], 0, 0, 0);
    __syncthreads();
  }
#pragma unroll
  for (int m = 0; m < 4; ++m) {
#pragma unroll
    for (int r = 0; r < 4; ++r) {
      int c = c0 + wr + m * 16 + g * 4 + r;
      float bi = bias[c];
#pragma unroll
      for (int n = 0; n < 4; ++n) {
        int nn = n0 + wc + n * 16 + ln;
        float val = (acc[m][n][r] + bi) * escale;
        if (OMODE == 0)
          ((u16*)Out)[((b * 16 + (c & 15)) * 1024 + nn) * 64 + (c >> 4)] = f2bf(val);
        else if (OMODE == 1)
          ((u16*)Out)[((b * 16 + (c & 15)) * 64 + (c >> 4)) * 1024 + nn] = f2bf(val);
        else
          ((float*)Out)[(b << 20) + (size_t)c * 1024 + nn] = val;
      }
    }
  }
}

// ---------------------------------------------------------------------------
// Flash attention per (b, h, 64-row q-tile). Q,K in [b][h][n][d], V in
// [b][h][d][n]. Computes S^T = mfma(K,Q) (lane col = nq), online softmax with
// cross-lane reduce, P staged via per-wave padded LDS, PV = mfma(P,V^T).
// Output Xh [b][h][n][d] bf16.  grid (16 qt, 16 h, 8 b), block 256.
// ---------------------------------------------------------------------------
__global__ __launch_bounds__(256) void attn_kernel(const u16* __restrict__ Qh,
                                                   const u16* __restrict__ Kh,
                                                   const u16* __restrict__ Vt,
                                                   u16* __restrict__ Xh) {
  __shared__ u16 Ks[64 * 72];
  __shared__ u16 Vs[64 * 72];
  __shared__ u16 Ps[4 * 16 * 72];
  int tid = threadIdx.x;
  int w = tid >> 6;
  int l = tid & 63, ln = l & 15, g = l >> 4;
  int qt = blockIdx.x, h = blockIdx.y, b = blockIdx.z;
  size_t hoff = ((size_t)b * 16 + h) * 65536;
  const u16* Qg = Qh + hoff;
  const u16* Kg = Kh + hoff;
  const u16* Vg = Vt + hoff;
  bf16x8 qf[2];
#pragma unroll
  for (int kk = 0; kk < 2; ++kk)
    qf[kk] = *(const bf16x8*)(Qg + (size_t)(qt * 64 + w * 16 + ln) * 64 + kk * 32 + g * 8);
  f32x4 xacc[4] = {};
  float m_run = -1e30f, l_run = 0.f;
  int sr = tid >> 3, so = (tid & 7) * 8;
  for (int kt = 0; kt < 16; ++kt) {
    __syncthreads();
#pragma unroll
    for (int i = 0; i < 2; ++i) {
      int r = sr + i * 32;
      int4 kv = *(const int4*)(Kg + (size_t)(kt * 64 + r) * 64 + so);
      int4 vv = *(const int4*)(Vg + (size_t)r * 1024 + kt * 64 + so);
      *(int4*)((char*)Ks + (r * 72 + so) * 2) = kv;
      *(int4*)((char*)Vs + (r * 72 + so) * 2) = vv;
    }
    __syncthreads();
    f32x4 sacc[4] = {};
#pragma unroll
    for (int kk = 0; kk < 2; ++kk) {
#pragma unroll
      for (int f = 0; f < 4; ++f) {
        bf16x8 kf = *(const bf16x8*)&Ks[(f * 16 + ln) * 72 + kk * 32 + g * 8];
        sacc[f] = __builtin_amdgcn_mfma_f32_16x16x32_bf16(kf, qf[kk], sacc[f], 0, 0, 0);
      }
    }
    float tmax = -1e30f;
#pragma unroll
    for (int f = 0; f < 4; ++f)
#pragma unroll
      for (int r = 0; r < 4; ++r) tmax = fmaxf(tmax, sacc[f][r]);
    tmax = fmaxf(tmax, __shfl_xor(tmax, 16));
    tmax = fmaxf(tmax, __shfl_xor(tmax, 32));
    float m_new = fmaxf(m_run, tmax);
    float alpha = __expf(m_run - m_new);
    float psum = 0.f;
#pragma unroll
    for (int f = 0; f < 4; ++f) {
      float p0 = __expf(sacc[f][0] - m_new);
      float p1 = __expf(sacc[f][1] - m_new);
      float p2 = __expf(sacc[f][2] - m_new);
      float p3 = __expf(sacc[f][3] - m_new);
      psum += (p0 + p1) + (p2 + p3);
      uint2 pk = make_uint2((u32)f2bf(p0) | ((u32)f2bf(p1) << 16),
                            (u32)f2bf(p2) | ((u32)f2bf(p3) << 16));
      *(uint2*)((char*)Ps + (w * 16 + ln) * 144 + f * 32 + g * 8) = pk;
    }
    psum += __shfl_xor(psum, 16);
    psum += __shfl_xor(psum, 32);
    l_run = l_run * alpha + psum;
    m_run = m_new;
    float al[4];
#pragma unroll
    for (int r = 0; r < 4; ++r) al[r] = __shfl(alpha, g * 4 + r);
#pragma unroll
    for (int fd = 0; fd < 4; ++fd)
#pragma unroll
      for (int r = 0; r < 4; ++r) xacc[fd][r] *= al[r];
#pragma unroll
    for (int kk = 0; kk < 2; ++kk) {
      bf16x8 pf = *(const bf16x8*)&Ps[(w * 16 + ln) * 72 + kk * 32 + g * 8];
#pragma unroll
      for (int fd = 0; fd < 4; ++fd) {
        bf16x8 vf = *(const bf16x8*)&Vs[(fd * 16 + ln) * 72 + kk * 32 + g * 8];
        xacc[fd] = __builtin_amdgcn_mfma_f32_16x16x32_bf16(pf, vf, xacc[fd], 0, 0, 0);
      }
    }
  }
  float il[4];
#pragma unroll
  for (int r = 0; r < 4; ++r) il[r] = 1.0f / __shfl(l_run, g * 4 + r);
#pragma unroll
  for (int fd = 0; fd < 4; ++fd) {
#pragma unroll
    for (int r = 0; r < 4; ++r) {
      int nq = qt * 64 + w * 16 + g * 4 + r;
      int d = fd * 16 + ln;
      Xh[hoff + (size_t)nq * 64 + d] = f2bf(xacc[fd][r] * il[r]);
    }
  }
}

// ---------------------------------------------------------------------------
extern "C" void kernel_launch(void* const* d_in, const int* in_sizes, int n_in,
                              void* d_out, int out_size, void* d_ws, size_t ws_size,
                              hipStream_t stream) {
  const float* q  = (const float*)d_in[0];
  const float* k  = (const float*)d_in[1];
  const float* v  = (const float*)d_in[2];
  const float* Wq = (const float*)d_in[3];
  const float* bq = (const float*)d_in[4];
  const float* Wk = (const float*)d_in[5];
  const float* bk = (const float*)d_in[6];
  const float* Wv = (const float*)d_in[7];
  const float* bv = (const float*)d_in[8];
  const float* Wm = (const float*)d_in[9];
  const float* bm = (const float*)d_in[10];

  char* ws = (char*)d_ws;
  u16* Wbf = (u16*)ws;                      //  8 MB: Wq,Wk,Wv,Wm' bf16
  u16* Qh  = (u16*)(ws + (8ull << 20));     // 16 MB [b][h][n][d]
  u16* Kh  = (u16*)(ws + (24ull << 20));    // 16 MB [b][h][n][d]
  u16* Vt  = (u16*)(ws + (40ull << 20));    // 16 MB [b][h][d][n]
  u16* Xt  = (u16*)(ws + (56ull << 20));    // 16 MB, reused (Xt then Xh)

  cast_weights<<<dim3(1024, 4, 1), 256, 0, stream>>>(Wq, Wk, Wv, Wm, Wbf);

  dim3 tg(16, 16, 8), gg(8, 8, 8), ag(16, 16, 8);

  transpose_cast<<<tg, 256, 0, stream>>>(q, Xt);
  gemm_bt<0, 0><<<gg, 256, 0, stream>>>(Wbf, Xt, bq, Qh, 0.125f);  // scale folded into Q
  transpose_cast<<<tg, 256, 0, stream>>>(k, Xt);
  gemm_bt<0, 0><<<gg, 256, 0, stream>>>(Wbf + (1u << 20), Xt, bk, Kh, 1.0f);
  transpose_cast<<<tg, 256, 0, stream>>>(v, Xt);
  gemm_bt<0, 1><<<gg, 256, 0, stream>>>(Wbf + (2u << 20), Xt, bv, Vt, 1.0f);

  attn_kernel<<<ag, 256, 0, stream>>>(Qh, Kh, Vt, Xt);

  gemm_bt<1, 2><<<gg, 256, 0, stream>>>(Wbf + (3u << 20), Xt, bm, d_out, 1.0f);
}

// Round 3
// 266.696 us; speedup vs baseline: 1.1119x; 1.1119x over previous
//
#include <hip/hip_runtime.h>

typedef __bf16 bf16x8 __attribute__((ext_vector_type(8)));
typedef __bf16 bf16x4 __attribute__((ext_vector_type(4)));
typedef float f32x4 __attribute__((ext_vector_type(4)));
typedef unsigned short u16;
typedef unsigned int u32;

__device__ __forceinline__ u16 f2bf(float f) {
  u32 u = __builtin_bit_cast(u32, f);
  u = (u + 0x7FFFu + ((u >> 16) & 1u)) >> 16;
  return (u16)u;
}

__device__ __forceinline__ void gload_lds16(const void* g, void* l) {
  __builtin_amdgcn_global_load_lds((const __attribute__((address_space(1))) void*)g,
                                   (__attribute__((address_space(3))) void*)l, 16, 0, 0);
}

// ---------------------------------------------------------------------------
// Transpose + cast: src fp32 [b][1024 i][1024 n] -> dst bf16 [b][1024 n][1024 i]
// grid (16 n-tiles, 16 i-tiles, 8 b), block 256
// ---------------------------------------------------------------------------
__global__ __launch_bounds__(256) void transpose_cast(const float* __restrict__ src,
                                                      u16* __restrict__ dst) {
  __shared__ float T[64][68];
  int tid = threadIdx.x;
  int n0 = blockIdx.x * 64, i0 = blockIdx.y * 64;
  size_t boff = (size_t)blockIdx.z << 20;
  const float* s = src + boff;
  u16* d = dst + boff;
  int ir = tid >> 4, n4 = (tid & 15) * 4;
#pragma unroll
  for (int r = 0; r < 4; ++r) {
    int i_loc = ir + r * 16;
    float4 v = *(const float4*)(s + (size_t)(i0 + i_loc) * 1024 + n0 + n4);
    *(float4*)&T[i_loc][n4] = v;
  }
  __syncthreads();
  int nr = tid >> 3, i8 = (tid & 7) * 8;
#pragma unroll
  for (int r = 0; r < 2; ++r) {
    int n_loc = nr + r * 32;
    u32 pk[4];
#pragma unroll
    for (int j = 0; j < 4; ++j) {
      float f0 = T[i8 + 2 * j][n_loc];
      float f1 = T[i8 + 2 * j + 1][n_loc];
      pk[j] = (u32)f2bf(f0) | ((u32)f2bf(f1) << 16);
    }
    *(uint4*)(d + (size_t)(n0 + n_loc) * 1024 + i0 + i8) = make_uint4(pk[0], pk[1], pk[2], pk[3]);
  }
}

// ---------------------------------------------------------------------------
// Cast weights to bf16. w=0..2: Wq/Wk/Wv as-is [o][i]. w=3: Wm' permuted so
// column c' = h*64+d maps to Wm column d*16+h (head-major K for final GEMM).
// grid (1024 rows, 4 weights), block 256 (4 cols/thread)
// ---------------------------------------------------------------------------
__global__ __launch_bounds__(256) void cast_weights(const float* __restrict__ Wq,
                                                    const float* __restrict__ Wk,
                                                    const float* __restrict__ Wv,
                                                    const float* __restrict__ Wm,
                                                    u16* __restrict__ out) {
  int w = blockIdx.y;
  const float* src = (w == 0) ? Wq : (w == 1) ? Wk : (w == 2) ? Wv : Wm;
  u16* dst = out + ((size_t)w << 20);
  int o = blockIdx.x;
  int c4 = threadIdx.x * 4;
  float f[4];
  if (w < 3) {
    float4 v = *(const float4*)(src + (size_t)o * 1024 + c4);
    f[0] = v.x; f[1] = v.y; f[2] = v.z; f[3] = v.w;
  } else {
#pragma unroll
    for (int j = 0; j < 4; ++j) {
      int cp = c4 + j;
      f[j] = src[(size_t)o * 1024 + (cp & 63) * 16 + (cp >> 6)];
    }
  }
  u32 p0 = (u32)f2bf(f[0]) | ((u32)f2bf(f[1]) << 16);
  u32 p1 = (u32)f2bf(f[2]) | ((u32)f2bf(f[3]) << 16);
  *(uint2*)(dst + (size_t)o * 1024 + c4) = make_uint2(p0, p1);
}

// ---------------------------------------------------------------------------
// bt-GEMM: C[c,n] = sum_k A[c,k] * B^T[n,k] (+bias), 128x128 tile, BK=32,
// 4 waves (2x2 of 64x64), mfma 16x16x32 bf16, global_load_lds staging.
// BMODE 0: B^T = plain [b][n][k] (Xt).  BMODE 1: B^T[n][c'] from attention
//          output Xh[b][h][n][d] with c' = h*64+d.
// OMODE 0: bf16 -> [b][h][n][d] (Q,K)   OMODE 1: bf16 -> [b][h][d][n] (V)
// OMODE 2: fp32 -> [b][c][n] (final out)
// grid (8 n-tiles, 8 c-tiles, 8 b), block 256
// ---------------------------------------------------------------------------
template <int BMODE, int OMODE>
__global__ __launch_bounds__(256) void gemm_bt(const u16* __restrict__ A,
                                               const u16* __restrict__ Bsrc,
                                               const float* __restrict__ bias,
                                               void* __restrict__ Out, float escale) {
  __shared__ u16 As[128 * 32];
  __shared__ u16 Bs[128 * 32];
  int tid = threadIdx.x;
  int wave = tid >> 6;
  int l = tid & 63, ln = l & 15, g = l >> 4;
  int n0 = blockIdx.x * 128, c0 = blockIdx.y * 128;
  size_t b = blockIdx.z;
  const u16* Bb = Bsrc + (b << 20);
  int wr = (wave >> 1) * 64, wc = (wave & 1) * 64;
  f32x4 acc[4][4] = {};
  for (int kt = 0; kt < 32; ++kt) {
#pragma unroll
    for (int i = 0; i < 2; ++i) {
      int e = i * 256 + tid;
      int row = e >> 2;
      int ko = (e & 3) * 8;
      gload_lds16(A + (size_t)(c0 + row) * 1024 + kt * 32 + ko,
                  &As[(i * 256 + wave * 64) * 8]);
      const u16* gb;
      if (BMODE == 0)
        gb = Bb + (size_t)(n0 + row) * 1024 + kt * 32 + ko;
      else
        gb = Bb + ((size_t)(kt >> 1) << 16) + (size_t)(n0 + row) * 64 + (kt & 1) * 32 + ko;
      gload_lds16(gb, &Bs[(i * 256 + wave * 64) * 8]);
    }
    __syncthreads();
    bf16x8 af[4], bfr[4];
#pragma unroll
    for (int m = 0; m < 4; ++m) af[m] = *(const bf16x8*)&As[(wr + m * 16 + ln) * 32 + g * 8];
#pragma unroll
    for (int n = 0; n < 4; ++n) bfr[n] = *(const bf16x8*)&Bs[(wc + n * 16 + ln) * 32 + g * 8];
#pragma unroll
    for (int m = 0; m < 4; ++m)
#pragma unroll
      for (int n = 0; n < 4; ++n)
        acc[m][n] = __builtin_amdgcn_mfma_f32_16x16x32_bf16(af[m], bfr[n], acc[m][n], 0, 0, 0);
    __syncthreads();
  }
#pragma unroll
  for (int m = 0; m < 4; ++m) {
#pragma unroll
    for (int r = 0; r < 4; ++r) {
      int c = c0 + wr + m * 16 + g * 4 + r;
      float bi = bias[c];
#pragma unroll
      for (int n = 0; n < 4; ++n) {
        int nn = n0 + wc + n * 16 + ln;
        float val = (acc[m][n][r] + bi) * escale;
        if (OMODE == 0)
          ((u16*)Out)[((b * 16 + (c & 15)) * 1024 + nn) * 64 + (c >> 4)] = f2bf(val);
        else if (OMODE == 1)
          ((u16*)Out)[((b * 16 + (c & 15)) * 64 + (c >> 4)) * 1024 + nn] = f2bf(val);
        else
          ((float*)Out)[(b << 20) + (size_t)c * 1024 + nn] = val;
      }
    }
  }
}

// ---------------------------------------------------------------------------
// Flash attention v2: one block = (b,h, 128 q-rows). No-max softmax (scores
// pre-scaled by log2e/8 in the Q projection; exp2 accumulated unnormalized,
// single divide at the end). K/V double-buffered via global_load_lds with
// pre-swizzled source (slot ^= row&7) + XOR-swizzled ds_reads. XCD-bijective
// block swizzle: all 8 blocks of one (b,h) land on one XCD consecutively.
// grid 1024 blocks x 256 threads.
// ---------------------------------------------------------------------------
__global__ __launch_bounds__(256) void attn_kernel(const u16* __restrict__ Qh,
                                                   const u16* __restrict__ Kh,
                                                   const u16* __restrict__ Vt,
                                                   u16* __restrict__ Xh) {
  __shared__ u16 Ks[2][4096];
  __shared__ u16 Vs[2][4096];
  __shared__ u16 Ps[8][16 * 72];  // [wave*2+tile][q-row][key], padded stride 72
  int tid = threadIdx.x;
  int w = tid >> 6, l = tid & 63, ln = l & 15, g = l >> 4;
  int id = blockIdx.x;
  int qp = (id & 63) >> 3;                 // q-pair index 0..7 (128 rows each)
  int bh = ((id >> 6) << 3) | (id & 7);    // xcd = id%8 = bh&7
  size_t hoff = (size_t)bh << 16;
  const u16* Qg = Qh + hoff;
  const u16* Kg = Kh + hoff;
  const u16* Vg = Vt + hoff;
  u16* Og = Xh + hoff;

  bf16x8 qf[2][2];
#pragma unroll
  for (int t = 0; t < 2; ++t)
#pragma unroll
    for (int kk = 0; kk < 2; ++kk)
      qf[t][kk] = *(const bf16x8*)(Qg + (size_t)(qp * 128 + t * 64 + w * 16 + ln) * 64 + kk * 32 + g * 8);

  // staging: wave w covers rows w*16 .. w*16+15 of the 64-row K/V tile
  int lr = l >> 3;                    // sub-row 0..7
  int sw8 = ((l & 7) ^ lr) << 3;      // swizzled 8-elem slot in source
  int r0 = w * 16 + lr, r1 = r0 + 8;
  const u16* kS0 = Kg + r0 * 64 + sw8;
  const u16* kS1 = Kg + r1 * 64 + sw8;
  const u16* vS0 = Vg + (size_t)r0 * 1024 + sw8;
  const u16* vS1 = Vg + (size_t)r1 * 1024 + sw8;

  f32x4 xacc[2][4] = {};
  float lacc[2] = {0.f, 0.f};

  gload_lds16(kS0, &Ks[0][(w * 2) * 512]);
  gload_lds16(kS1, &Ks[0][(w * 2 + 1) * 512]);
  gload_lds16(vS0, &Vs[0][(w * 2) * 512]);
  gload_lds16(vS1, &Vs[0][(w * 2 + 1) * 512]);
  __syncthreads();

  int sx = ln & 7;
  int cur = 0;
  for (int kt = 0; kt < 16; ++kt) {
    if (kt < 15) {
      int nxt = cur ^ 1;
      gload_lds16(kS0 + (kt + 1) * 4096, &Ks[nxt][(w * 2) * 512]);
      gload_lds16(kS1 + (kt + 1) * 4096, &Ks[nxt][(w * 2 + 1) * 512]);
      gload_lds16(vS0 + (kt + 1) * 64, &Vs[nxt][(w * 2) * 512]);
      gload_lds16(vS1 + (kt + 1) * 64, &Vs[nxt][(w * 2 + 1) * 512]);
    }
    bf16x8 kf[2][4], vf[2][4];
#pragma unroll
    for (int kk = 0; kk < 2; ++kk)
#pragma unroll
      for (int f = 0; f < 4; ++f) {
        int slot = (((kk << 2) + g) ^ sx) << 3;
        kf[kk][f] = *(const bf16x8*)&Ks[cur][(f * 16 + ln) * 64 + slot];
        vf[kk][f] = *(const bf16x8*)&Vs[cur][(f * 16 + ln) * 64 + slot];
      }
    f32x4 sacc[2][4] = {};
#pragma unroll
    for (int t = 0; t < 2; ++t)
#pragma unroll
      for (int kk = 0; kk < 2; ++kk)
#pragma unroll
        for (int f = 0; f < 4; ++f)
          sacc[t][f] = __builtin_amdgcn_mfma_f32_16x16x32_bf16(kf[kk][f], qf[t][kk], sacc[t][f], 0, 0, 0);
#pragma unroll
    for (int t = 0; t < 2; ++t) {
      u16* PsW = Ps[w * 2 + t];
#pragma unroll
      for (int f = 0; f < 4; ++f) {
        float p0 = __builtin_amdgcn_exp2f(sacc[t][f][0]);
        float p1 = __builtin_amdgcn_exp2f(sacc[t][f][1]);
        float p2 = __builtin_amdgcn_exp2f(sacc[t][f][2]);
        float p3 = __builtin_amdgcn_exp2f(sacc[t][f][3]);
        lacc[t] += (p0 + p1) + (p2 + p3);
        bf16x4 pb;
        pb[0] = (__bf16)p0; pb[1] = (__bf16)p1; pb[2] = (__bf16)p2; pb[3] = (__bf16)p3;
        *(bf16x4*)&PsW[ln * 72 + (f << 4) + (g << 2)] = pb;
      }
    }
#pragma unroll
    for (int t = 0; t < 2; ++t) {
      const u16* PsR = Ps[w * 2 + t];
#pragma unroll
      for (int kk = 0; kk < 2; ++kk) {
        bf16x8 pf = *(const bf16x8*)&PsR[ln * 72 + (kk << 5) + (g << 3)];
#pragma unroll
        for (int fd = 0; fd < 4; ++fd)
          xacc[t][fd] = __builtin_amdgcn_mfma_f32_16x16x32_bf16(pf, vf[kk][fd], xacc[t][fd], 0, 0, 0);
      }
    }
    __syncthreads();
    cur ^= 1;
  }

#pragma unroll
  for (int t = 0; t < 2; ++t) {
    float lt = lacc[t];
    lt += __shfl_xor(lt, 16);
    lt += __shfl_xor(lt, 32);
    float il[4];
#pragma unroll
    for (int r = 0; r < 4; ++r) il[r] = 1.0f / __shfl(lt, g * 4 + r);
#pragma unroll
    for (int fd = 0; fd < 4; ++fd)
#pragma unroll
      for (int r = 0; r < 4; ++r) {
        int nq = qp * 128 + t * 64 + w * 16 + g * 4 + r;
        Og[(size_t)nq * 64 + fd * 16 + ln] = f2bf(xacc[t][fd][r] * il[r]);
      }
  }
}

// ---------------------------------------------------------------------------
extern "C" void kernel_launch(void* const* d_in, const int* in_sizes, int n_in,
                              void* d_out, int out_size, void* d_ws, size_t ws_size,
                              hipStream_t stream) {
  const float* q  = (const float*)d_in[0];
  const float* k  = (const float*)d_in[1];
  const float* v  = (const float*)d_in[2];
  const float* Wq = (const float*)d_in[3];
  const float* bq = (const float*)d_in[4];
  const float* Wk = (const float*)d_in[5];
  const float* bk = (const float*)d_in[6];
  const float* Wv = (const float*)d_in[7];
  const float* bv = (const float*)d_in[8];
  const float* Wm = (const float*)d_in[9];
  const float* bm = (const float*)d_in[10];

  char* ws = (char*)d_ws;
  u16* Wbf = (u16*)ws;                      //  8 MB: Wq,Wk,Wv,Wm' bf16
  u16* Qh  = (u16*)(ws + (8ull << 20));     // 16 MB [b][h][n][d]
  u16* Kh  = (u16*)(ws + (24ull << 20));    // 16 MB [b][h][n][d]
  u16* Vt  = (u16*)(ws + (40ull << 20));    // 16 MB [b][h][d][n]
  u16* Xt  = (u16*)(ws + (56ull << 20));    // 16 MB, reused (Xt then Xh)

  cast_weights<<<dim3(1024, 4, 1), 256, 0, stream>>>(Wq, Wk, Wv, Wm, Wbf);

  dim3 tg(16, 16, 8), gg(8, 8, 8);

  // Q scale = 1/sqrt(64) * log2(e), folded so attention uses raw exp2
  const float qscale = 0.125f * 1.44269504088896340736f;

  transpose_cast<<<tg, 256, 0, stream>>>(q, Xt);
  gemm_bt<0, 0><<<gg, 256, 0, stream>>>(Wbf, Xt, bq, Qh, qscale);
  transpose_cast<<<tg, 256, 0, stream>>>(k, Xt);
  gemm_bt<0, 0><<<gg, 256, 0, stream>>>(Wbf + (1u << 20), Xt, bk, Kh, 1.0f);
  transpose_cast<<<tg, 256, 0, stream>>>(v, Xt);
  gemm_bt<0, 1><<<gg, 256, 0, stream>>>(Wbf + (2u << 20), Xt, bv, Vt, 1.0f);

  attn_kernel<<<1024, 256, 0, stream>>>(Qh, Kh, Vt, Xt);

  gemm_bt<1, 2><<<gg, 256, 0, stream>>>(Wbf + (3u << 20), Xt, bm, d_out, 1.0f);
}